// Round 8
// baseline (296.780 us; speedup 1.0000x reference)
//
#include <hip/hip_runtime.h>

#define HID 20
#define NLAY 7

// Pin a value into an AGPR (write) / pull it back (read).
#define AGPR_WRITE(dst, src) asm("v_accvgpr_write_b32 %0, %1" : "=a"(dst) : "v"(src))
#define AGPR_READ(dst, src)  asm("v_accvgpr_read_b32 %0, %1" : "=v"(dst) : "a"(src))

// tanh and its first three derivatives, via one hardware exp.
__device__ __forceinline__ float tanh_derivs(float a, float& d1, float& d2, float& d3) {
    const float e = __expf(2.0f * a);
    const float s = 1.0f - __fdividef(2.0f, e + 1.0f);
    d1 = 1.0f - s * s;               // f'
    d2 = -2.0f * s * d1;             // f''
    d3 = -2.0f * (d1 * d1 + s * d2); // f'''
    return s;
}

// ---------------- Kernel A: spatial jet, 8 comps ----------------
// 0=val 1=gx 2=gy 3=hxx 4=hxy 5=hyy 6=Lx 7=Ly
#define NCA 8

__global__ void __launch_bounds__(256, 1)
pinnA(const float* __restrict__ xs, const float* __restrict__ ys, const float* __restrict__ ts,
      const float* __restrict__ W_in, const float* __restrict__ b_in,
      const float* __restrict__ W_hid, const float* __restrict__ b_hid,
      const float* __restrict__ W_out, const float* __restrict__ b_out,
      const float* __restrict__ lam1p, const float* __restrict__ lam2p,
      float* __restrict__ out, int N)
{
    const int idx = blockIdx.x * blockDim.x + threadIdx.x;
    if (idx >= N) return;
    const float xv = xs[idx], yv = ys[idx], tv = ts[idx];
    const float l1 = lam1p[0], l2 = lam2p[0];

    float hA_[HID][NCA];  // jet state, AGPR-pinned

    #pragma unroll
    for (int j = 0; j < HID; ++j) {
        const float w0 = W_in[j], w1 = W_in[HID + j], w2 = W_in[2 * HID + j];
        const float a0 = fmaf(xv, w0, fmaf(yv, w1, fmaf(tv, w2, b_in[j])));
        float d1, d2, d3;
        const float s = tanh_derivs(a0, d1, d2, d3);
        const float g2w = w0 * w0 + w1 * w1;
        float nv[NCA];
        nv[0] = s;
        nv[1] = d1 * w0;
        nv[2] = d1 * w1;
        nv[3] = d2 * w0 * w0;
        nv[4] = d2 * w0 * w1;
        nv[5] = d2 * w1 * w1;
        nv[6] = d3 * w0 * g2w;
        nv[7] = d3 * w1 * g2w;
        #pragma unroll
        for (int c = 0; c < NCA; ++c) AGPR_WRITE(hA_[j][c], nv[c]);
    }

    #pragma unroll 1
    for (int l = 0; l < NLAY; ++l) {
        const float* __restrict__ Wl = W_hid + l * HID * HID;
        const float* __restrict__ bl = b_hid + l * HID;
        float acc[HID][NCA];  // 160 VGPR, RMW, all-VGPR
        #pragma unroll
        for (int j = 0; j < HID; ++j) {
            acc[j][0] = bl[j];
            #pragma unroll
            for (int c = 1; c < NCA; ++c) acc[j][c] = 0.0f;
        }
        #pragma unroll
        for (int i = 0; i < HID; ++i) {
            float r[NCA];
            #pragma unroll
            for (int c = 0; c < NCA; ++c) AGPR_READ(r[c], hA_[i][c]);
            #pragma unroll
            for (int j = 0; j < HID; ++j) {
                const float w = Wl[i * HID + j];
                #pragma unroll
                for (int c = 0; c < NCA; ++c) acc[j][c] = fmaf(w, r[c], acc[j][c]);
            }
        }
        #pragma unroll
        for (int j = 0; j < HID; ++j) {
            float d1, d2, d3;
            const float s = tanh_derivs(acc[j][0], d1, d2, d3);
            const float gx = acc[j][1], gy = acc[j][2];
            const float hxx = acc[j][3], hxy = acc[j][4], hyy = acc[j][5];
            const float g2 = gx * gx + gy * gy;
            float nv[NCA];
            nv[0] = s;
            nv[1] = d1 * gx;
            nv[2] = d1 * gy;
            nv[3] = fmaf(d2, gx * gx, d1 * hxx);
            nv[4] = fmaf(d2, gx * gy, d1 * hxy);
            nv[5] = fmaf(d2, gy * gy, d1 * hyy);
            nv[6] = d3 * gx * g2 + d2 * (3.0f * gx * hxx + 2.0f * gy * hxy + gx * hyy) + d1 * acc[j][6];
            nv[7] = d3 * gy * g2 + d2 * (3.0f * gy * hyy + 2.0f * gx * hxy + gy * hxx) + d1 * acc[j][7];
            #pragma unroll
            for (int c = 0; c < NCA; ++c) AGPR_WRITE(hA_[j][c], nv[c]);
        }
    }

    float su = 0, sv = 0, sp = 0, sux = 0, suy = 0, svx = 0;
    float spx = 0, spy = 0, slx = 0, sly = 0;
    #pragma unroll
    for (int i = 0; i < HID; ++i) {
        const float w0 = W_out[2 * i], w1 = W_out[2 * i + 1];
        float r[NCA];
        #pragma unroll
        for (int c = 0; c < NCA; ++c) AGPR_READ(r[c], hA_[i][c]);
        sp  = fmaf(w1, r[0], sp);
        sv  = fmaf(w0, r[1], sv);   // psi_x
        su  = fmaf(w0, r[2], su);   // psi_y
        spx = fmaf(w1, r[1], spx);
        spy = fmaf(w1, r[2], spy);
        svx = fmaf(w0, r[3], svx);  // psi_xx
        sux = fmaf(w0, r[4], sux);  // psi_xy
        suy = fmaf(w0, r[5], suy);  // psi_yy
        slx = fmaf(w0, r[6], slx);
        sly = fmaf(w0, r[7], sly);
    }

    const float u = su, v = -sv, p = sp + b_out[1];
    const float ux = sux, uy = suy, vx = -svx, vy = -sux;
    const float px = spx, py = spy;

    const float fuP = l1 * (u * ux + v * uy) + px - l2 * sly;
    const float fvP = l1 * (u * vx + v * vy) + py + l2 * slx;

    out[idx]         = u;
    out[N + idx]     = v;
    out[2 * N + idx] = p;
    out[3 * N + idx] = fuP;
    out[4 * N + idx] = fvP;
}

// ---------------- Kernel B: time jet, 6 comps ----------------
// 0=val 1=gx 2=gy 3=gt 4=hxt 5=hyt
#define NCB 6

__global__ void __launch_bounds__(256, 1)
pinnB(const float* __restrict__ xs, const float* __restrict__ ys, const float* __restrict__ ts,
      const float* __restrict__ W_in, const float* __restrict__ b_in,
      const float* __restrict__ W_hid, const float* __restrict__ b_hid,
      const float* __restrict__ W_out,
      float* __restrict__ out, int N)
{
    const int idx = blockIdx.x * blockDim.x + threadIdx.x;
    if (idx >= N) return;
    const float xv = xs[idx], yv = ys[idx], tv = ts[idx];

    float hB_[HID][NCB];  // jet state, AGPR-pinned

    #pragma unroll
    for (int j = 0; j < HID; ++j) {
        const float w0 = W_in[j], w1 = W_in[HID + j], w2 = W_in[2 * HID + j];
        const float a0 = fmaf(xv, w0, fmaf(yv, w1, fmaf(tv, w2, b_in[j])));
        float d1, d2, d3;
        const float s = tanh_derivs(a0, d1, d2, d3);
        float nv[NCB];
        nv[0] = s;
        nv[1] = d1 * w0;
        nv[2] = d1 * w1;
        nv[3] = d1 * w2;
        nv[4] = d2 * w0 * w2;
        nv[5] = d2 * w1 * w2;
        #pragma unroll
        for (int c = 0; c < NCB; ++c) AGPR_WRITE(hB_[j][c], nv[c]);
    }

    #pragma unroll 1
    for (int l = 0; l < NLAY; ++l) {
        const float* __restrict__ Wl = W_hid + l * HID * HID;
        const float* __restrict__ bl = b_hid + l * HID;
        float acc[HID][NCB];  // 120 VGPR
        #pragma unroll
        for (int j = 0; j < HID; ++j) {
            acc[j][0] = bl[j];
            #pragma unroll
            for (int c = 1; c < NCB; ++c) acc[j][c] = 0.0f;
        }
        #pragma unroll
        for (int i = 0; i < HID; ++i) {
            float r[NCB];
            #pragma unroll
            for (int c = 0; c < NCB; ++c) AGPR_READ(r[c], hB_[i][c]);
            #pragma unroll
            for (int j = 0; j < HID; ++j) {
                const float w = Wl[i * HID + j];
                #pragma unroll
                for (int c = 0; c < NCB; ++c) acc[j][c] = fmaf(w, r[c], acc[j][c]);
            }
        }
        #pragma unroll
        for (int j = 0; j < HID; ++j) {
            float d1, d2, d3;
            const float s = tanh_derivs(acc[j][0], d1, d2, d3);
            const float gx = acc[j][1], gy = acc[j][2], gt = acc[j][3];
            float nv[NCB];
            nv[0] = s;
            nv[1] = d1 * gx;
            nv[2] = d1 * gy;
            nv[3] = d1 * gt;
            nv[4] = fmaf(d2, gx * gt, d1 * acc[j][4]);
            nv[5] = fmaf(d2, gy * gt, d1 * acc[j][5]);
            #pragma unroll
            for (int c = 0; c < NCB; ++c) AGPR_WRITE(hB_[j][c], nv[c]);
        }
    }

    float pxt = 0.0f, pyt = 0.0f;
    #pragma unroll
    for (int i = 0; i < HID; ++i) {
        const float w0 = W_out[2 * i];
        float r4, r5;
        AGPR_READ(r4, hB_[i][4]);
        AGPR_READ(r5, hB_[i][5]);
        pxt = fmaf(w0, r4, pxt);
        pyt = fmaf(w0, r5, pyt);
    }

    out[3 * N + idx] += pyt;   // += u_t
    out[4 * N + idx] += -pxt;  // += v_t
}

extern "C" void kernel_launch(void* const* d_in, const int* in_sizes, int n_in,
                              void* d_out, int out_size, void* d_ws, size_t ws_size,
                              hipStream_t stream) {
    const float* xs    = (const float*)d_in[0];
    const float* ys    = (const float*)d_in[1];
    const float* ts    = (const float*)d_in[2];
    const float* W_in  = (const float*)d_in[3];
    const float* b_in  = (const float*)d_in[4];
    const float* W_hid = (const float*)d_in[5];
    const float* b_hid = (const float*)d_in[6];
    const float* W_out = (const float*)d_in[7];
    const float* b_out = (const float*)d_in[8];
    const float* lam1  = (const float*)d_in[9];
    const float* lam2  = (const float*)d_in[10];
    float* out = (float*)d_out;

    const int N = in_sizes[0];
    const int block = 256;
    const int grid = (N + block - 1) / block;
    pinnA<<<grid, block, 0, stream>>>(xs, ys, ts, W_in, b_in, W_hid, b_hid,
                                      W_out, b_out, lam1, lam2, out, N);
    pinnB<<<grid, block, 0, stream>>>(xs, ys, ts, W_in, b_in, W_hid, b_hid,
                                      W_out, out, N);
}

// Round 9
// 229.536 us; speedup vs baseline: 1.2930x; 1.2930x over previous
//
#include <hip/hip_runtime.h>

#define HID 20
#define NLAY 7
#define HHID 10

// Pin a value into an AGPR (write) / pull it back (read).
#define AGPR_WRITE(dst, src) asm("v_accvgpr_write_b32 %0, %1" : "=a"(dst) : "v"(src))
#define AGPR_READ(dst, src)  asm("v_accvgpr_read_b32 %0, %1" : "=v"(dst) : "a"(src))

// tanh and its first three derivatives, via one hardware exp.
__device__ __forceinline__ float tanh_derivs(float a, float& d1, float& d2, float& d3) {
    const float e = __expf(2.0f * a);
    const float s = 1.0f - __fdividef(2.0f, e + 1.0f);
    d1 = 1.0f - s * s;               // f'
    d2 = -2.0f * s * d1;             // f''
    d3 = -2.0f * (d1 * d1 + s * d2); // f'''
    return s;
}

// ---------------- Kernel A: spatial jet, 8 comps, half-split acc ----------------
// 0=val 1=gx 2=gy 3=hxx 4=hxy 5=hyy 6=Lx 7=Ly
#define NCA 8

__global__ void __launch_bounds__(256, 1)
pinnA(const float* __restrict__ xs, const float* __restrict__ ys, const float* __restrict__ ts,
      const float* __restrict__ W_in, const float* __restrict__ b_in,
      const float* __restrict__ W_hid, const float* __restrict__ b_hid,
      const float* __restrict__ W_out, const float* __restrict__ b_out,
      const float* __restrict__ lam1p, const float* __restrict__ lam2p,
      float* __restrict__ out, int N)
{
    const int idx = blockIdx.x * blockDim.x + threadIdx.x;
    if (idx >= N) return;
    const float xv = xs[idx], yv = ys[idx], tv = ts[idx];
    const float l1 = lam1p[0], l2 = lam2p[0];

    float hA_[HID][NCA];   // jet state X (AGPR-pinned)
    float yA_[HHID][NCA];  // first-half stash Y (AGPR-pinned)

    #pragma unroll
    for (int j = 0; j < HID; ++j) {
        const float w0 = W_in[j], w1 = W_in[HID + j], w2 = W_in[2 * HID + j];
        const float a0 = fmaf(xv, w0, fmaf(yv, w1, fmaf(tv, w2, b_in[j])));
        float d1, d2, d3;
        const float s = tanh_derivs(a0, d1, d2, d3);
        const float g2w = w0 * w0 + w1 * w1;
        float nv[NCA];
        nv[0] = s;
        nv[1] = d1 * w0;
        nv[2] = d1 * w1;
        nv[3] = d2 * w0 * w0;
        nv[4] = d2 * w0 * w1;
        nv[5] = d2 * w1 * w1;
        nv[6] = d3 * w0 * g2w;
        nv[7] = d3 * w1 * g2w;
        #pragma unroll
        for (int c = 0; c < NCA; ++c) AGPR_WRITE(hA_[j][c], nv[c]);
    }

    #pragma unroll 1
    for (int l = 0; l < NLAY; ++l) {
        const float* __restrict__ Wl = W_hid + l * HID * HID;
        const float* __restrict__ bl = b_hid + l * HID;

        #pragma unroll
        for (int hf = 0; hf < 2; ++hf) {
            float acc[HHID][NCA];  // 80 VGPR hot
            #pragma unroll
            for (int j = 0; j < HHID; ++j) {
                acc[j][0] = bl[hf * HHID + j];
                #pragma unroll
                for (int c = 1; c < NCA; ++c) acc[j][c] = 0.0f;
            }
            #pragma unroll
            for (int i = 0; i < HID; ++i) {
                float r[NCA];
                #pragma unroll
                for (int c = 0; c < NCA; ++c) AGPR_READ(r[c], hA_[i][c]);
                #pragma unroll
                for (int j = 0; j < HHID; ++j) {
                    const float w = Wl[i * HID + hf * HHID + j];
                    #pragma unroll
                    for (int c = 0; c < NCA; ++c) acc[j][c] = fmaf(w, r[c], acc[j][c]);
                }
            }
            #pragma unroll
            for (int j = 0; j < HHID; ++j) {
                float d1, d2, d3;
                const float s = tanh_derivs(acc[j][0], d1, d2, d3);
                const float gx = acc[j][1], gy = acc[j][2];
                const float hxx = acc[j][3], hxy = acc[j][4], hyy = acc[j][5];
                const float g2 = gx * gx + gy * gy;
                float nv[NCA];
                nv[0] = s;
                nv[1] = d1 * gx;
                nv[2] = d1 * gy;
                nv[3] = fmaf(d2, gx * gx, d1 * hxx);
                nv[4] = fmaf(d2, gx * gy, d1 * hxy);
                nv[5] = fmaf(d2, gy * gy, d1 * hyy);
                nv[6] = d3 * gx * g2 + d2 * (3.0f * gx * hxx + 2.0f * gy * hxy + gx * hyy) + d1 * acc[j][6];
                nv[7] = d3 * gy * g2 + d2 * (3.0f * gy * hyy + 2.0f * gx * hxy + gy * hxx) + d1 * acc[j][7];
                if (hf == 0) {
                    #pragma unroll
                    for (int c = 0; c < NCA; ++c) AGPR_WRITE(yA_[j][c], nv[c]);
                } else {
                    #pragma unroll
                    for (int c = 0; c < NCA; ++c) AGPR_WRITE(hA_[HHID + j][c], nv[c]);
                }
            }
        }
        // commit stash: X[0..9] = Y
        #pragma unroll
        for (int j = 0; j < HHID; ++j) {
            #pragma unroll
            for (int c = 0; c < NCA; ++c) {
                float t;
                AGPR_READ(t, yA_[j][c]);
                AGPR_WRITE(hA_[j][c], t);
            }
        }
    }

    float su = 0, sv = 0, sp = 0, sux = 0, suy = 0, svx = 0;
    float spx = 0, spy = 0, slx = 0, sly = 0;
    #pragma unroll
    for (int i = 0; i < HID; ++i) {
        const float w0 = W_out[2 * i], w1 = W_out[2 * i + 1];
        float r[NCA];
        #pragma unroll
        for (int c = 0; c < NCA; ++c) AGPR_READ(r[c], hA_[i][c]);
        sp  = fmaf(w1, r[0], sp);
        sv  = fmaf(w0, r[1], sv);   // psi_x
        su  = fmaf(w0, r[2], su);   // psi_y
        spx = fmaf(w1, r[1], spx);
        spy = fmaf(w1, r[2], spy);
        svx = fmaf(w0, r[3], svx);  // psi_xx
        sux = fmaf(w0, r[4], sux);  // psi_xy
        suy = fmaf(w0, r[5], suy);  // psi_yy
        slx = fmaf(w0, r[6], slx);
        sly = fmaf(w0, r[7], sly);
    }

    const float u = su, v = -sv, p = sp + b_out[1];
    const float ux = sux, uy = suy, vx = -svx, vy = -sux;
    const float px = spx, py = spy;

    const float fuP = l1 * (u * ux + v * uy) + px - l2 * sly;
    const float fvP = l1 * (u * vx + v * vy) + py + l2 * slx;

    out[idx]         = u;
    out[N + idx]     = v;
    out[2 * N + idx] = p;
    out[3 * N + idx] = fuP;
    out[4 * N + idx] = fvP;
}

// ---------------- Kernel B: time jet, 6 comps (unchanged, at model speed) ----------------
// 0=val 1=gx 2=gy 3=gt 4=hxt 5=hyt
#define NCB 6

__global__ void __launch_bounds__(256, 1)
pinnB(const float* __restrict__ xs, const float* __restrict__ ys, const float* __restrict__ ts,
      const float* __restrict__ W_in, const float* __restrict__ b_in,
      const float* __restrict__ W_hid, const float* __restrict__ b_hid,
      const float* __restrict__ W_out,
      float* __restrict__ out, int N)
{
    const int idx = blockIdx.x * blockDim.x + threadIdx.x;
    if (idx >= N) return;
    const float xv = xs[idx], yv = ys[idx], tv = ts[idx];

    float hB_[HID][NCB];  // jet state, AGPR-pinned

    #pragma unroll
    for (int j = 0; j < HID; ++j) {
        const float w0 = W_in[j], w1 = W_in[HID + j], w2 = W_in[2 * HID + j];
        const float a0 = fmaf(xv, w0, fmaf(yv, w1, fmaf(tv, w2, b_in[j])));
        float d1, d2, d3;
        const float s = tanh_derivs(a0, d1, d2, d3);
        float nv[NCB];
        nv[0] = s;
        nv[1] = d1 * w0;
        nv[2] = d1 * w1;
        nv[3] = d1 * w2;
        nv[4] = d2 * w0 * w2;
        nv[5] = d2 * w1 * w2;
        #pragma unroll
        for (int c = 0; c < NCB; ++c) AGPR_WRITE(hB_[j][c], nv[c]);
    }

    #pragma unroll 1
    for (int l = 0; l < NLAY; ++l) {
        const float* __restrict__ Wl = W_hid + l * HID * HID;
        const float* __restrict__ bl = b_hid + l * HID;
        float acc[HID][NCB];  // 120 VGPR
        #pragma unroll
        for (int j = 0; j < HID; ++j) {
            acc[j][0] = bl[j];
            #pragma unroll
            for (int c = 1; c < NCB; ++c) acc[j][c] = 0.0f;
        }
        #pragma unroll
        for (int i = 0; i < HID; ++i) {
            float r[NCB];
            #pragma unroll
            for (int c = 0; c < NCB; ++c) AGPR_READ(r[c], hB_[i][c]);
            #pragma unroll
            for (int j = 0; j < HID; ++j) {
                const float w = Wl[i * HID + j];
                #pragma unroll
                for (int c = 0; c < NCB; ++c) acc[j][c] = fmaf(w, r[c], acc[j][c]);
            }
        }
        #pragma unroll
        for (int j = 0; j < HID; ++j) {
            float d1, d2, d3;
            const float s = tanh_derivs(acc[j][0], d1, d2, d3);
            const float gx = acc[j][1], gy = acc[j][2], gt = acc[j][3];
            float nv[NCB];
            nv[0] = s;
            nv[1] = d1 * gx;
            nv[2] = d1 * gy;
            nv[3] = d1 * gt;
            nv[4] = fmaf(d2, gx * gt, d1 * acc[j][4]);
            nv[5] = fmaf(d2, gy * gt, d1 * acc[j][5]);
            #pragma unroll
            for (int c = 0; c < NCB; ++c) AGPR_WRITE(hB_[j][c], nv[c]);
        }
    }

    float pxt = 0.0f, pyt = 0.0f;
    #pragma unroll
    for (int i = 0; i < HID; ++i) {
        const float w0 = W_out[2 * i];
        float r4, r5;
        AGPR_READ(r4, hB_[i][4]);
        AGPR_READ(r5, hB_[i][5]);
        pxt = fmaf(w0, r4, pxt);
        pyt = fmaf(w0, r5, pyt);
    }

    out[3 * N + idx] += pyt;   // += u_t
    out[4 * N + idx] += -pxt;  // += v_t
}

extern "C" void kernel_launch(void* const* d_in, const int* in_sizes, int n_in,
                              void* d_out, int out_size, void* d_ws, size_t ws_size,
                              hipStream_t stream) {
    const float* xs    = (const float*)d_in[0];
    const float* ys    = (const float*)d_in[1];
    const float* ts    = (const float*)d_in[2];
    const float* W_in  = (const float*)d_in[3];
    const float* b_in  = (const float*)d_in[4];
    const float* W_hid = (const float*)d_in[5];
    const float* b_hid = (const float*)d_in[6];
    const float* W_out = (const float*)d_in[7];
    const float* b_out = (const float*)d_in[8];
    const float* lam1  = (const float*)d_in[9];
    const float* lam2  = (const float*)d_in[10];
    float* out = (float*)d_out;

    const int N = in_sizes[0];
    const int block = 256;
    const int grid = (N + block - 1) / block;
    pinnA<<<grid, block, 0, stream>>>(xs, ys, ts, W_in, b_in, W_hid, b_hid,
                                      W_out, b_out, lam1, lam2, out, N);
    pinnB<<<grid, block, 0, stream>>>(xs, ys, ts, W_in, b_in, W_hid, b_hid,
                                      W_out, out, N);
}